// Round 2
// baseline (4462.989 us; speedup 1.0000x reference)
//
#include <hip/hip_runtime.h>

// ---------------------------------------------------------------------------
// GRU autoencoder: B=128, T=512, E=H=256.  (fp16 operand/weight precision,
// fp32 recurrent state held in registers.)
//  prep   : fp32->fp16 weight repack into MFMA fragment order + bias folding
//  gemm_gi: gi_x = x @ Wih_e^T + (bih_e + bhh_e[rz])   [65536 x 768] fp16
//  enc    : persistent recurrence, 8 WGs x 16 rows, Whh_e entirely in VGPRs
//  dec0   : decoder step 0 (input=latents, state=0) - needs unfused Wih_d
//  dec    : persistent recurrence, rz-sum trick (input==state for t>=1)
// ---------------------------------------------------------------------------

typedef unsigned short u16;
typedef unsigned int   u32;

typedef _Float16 f16x8 __attribute__((ext_vector_type(8)));
typedef float    f32x4 __attribute__((ext_vector_type(4)));

#define B_ 128
#define T_ 512
#define H_ 256
#define G3 768

// workspace layout (bytes)
#define GI_OFF     0ull                   // gi_x fp16 [65536][768]
#define WIH_OFF    100663296ull           // enc ih frag [48][8][64][8] fp16
#define WHH_OFF    101056512ull           // enc hh frag [48][8][64][8] fp16
#define WRZ_OFF    101449728ull           // dec rz-sum frag [32][8][64][8]
#define WIN_OFF    101711872ull           // dec in frag [16][8][64][8]
#define WHN_OFF    101842944ull           // dec hn frag [16][8][64][8]
#define BG_OFF     101974016ull           // gemm bias fp32 [768]
#define BHN_E_OFF  101977088ull           // enc bhh_n fp32 [256]
#define BDEC_OFF   101978112ull           // dec bias fp32 [1024] {brz,bin,bhn}
#define H1_OFF     101982208ull           // dec h1 fp32 [128][256]

#define DEC_LDS    143360                 // 128K whn + 8K h + 4K bias

__device__ __forceinline__ float h2f(u16 u) {
    return (float)__builtin_bit_cast(_Float16, u);
}
__device__ __forceinline__ u16 f2h(float f) {
    _Float16 h = (_Float16)f;             // v_cvt_f16_f32, RNE
    return __builtin_bit_cast(u16, h);
}
__device__ __forceinline__ float sigf(float x) {
    return __builtin_amdgcn_rcpf(1.f + __builtin_amdgcn_exp2f(x * -1.4426950408889634f));
}
__device__ __forceinline__ float tanhf_(float x) {
    return 1.f - 2.f * __builtin_amdgcn_rcpf(1.f + __builtin_amdgcn_exp2f(x * 2.8853900817779268f));
}
__device__ __forceinline__ f16x8 ldfrag(const u16* base, int nt, int ks, int l) {
    return __builtin_bit_cast(f16x8, *(const uint4*)(base + ((size_t)((nt * 8 + ks) * 64 + l)) * 8));
}

// ---------------------------------------------------------------------------
// prep: pack weights into fragment order  W[nt*16 + lane%16][ks*32 + (lane/16)*8 + j]
// ---------------------------------------------------------------------------
__global__ __launch_bounds__(256) void prep_kernel(
    const float* __restrict__ Wih_e, const float* __restrict__ Whh_e,
    const float* __restrict__ bih_e, const float* __restrict__ bhh_e,
    const float* __restrict__ Wih_d, const float* __restrict__ Whh_d,
    const float* __restrict__ bih_d, const float* __restrict__ bhh_d,
    char* ws)
{
    int gid = blockIdx.x * 256 + threadIdx.x;
    const int NFRAG = 160 * 8 * 64;
    if (gid < NFRAG) {
        int lane = gid & 63;
        int ks = (gid >> 6) & 7;
        int a = gid >> 9;
        int lm = lane & 15, lg = lane >> 4;
        int k0 = ks * 32 + lg * 8;
        const float* s0; const float* s1 = nullptr; u16* dst; int nt;
        if (a < 48)       { nt = a;       s0 = Wih_e + (size_t)(nt*16+lm)*256 + k0;            dst = (u16*)(ws + WIH_OFF); }
        else if (a < 96)  { nt = a - 48;  s0 = Whh_e + (size_t)(nt*16+lm)*256 + k0;            dst = (u16*)(ws + WHH_OFF); }
        else if (a < 128) { nt = a - 96;  s0 = Wih_d + (size_t)(nt*16+lm)*256 + k0;
                            s1 = Whh_d + (size_t)(nt*16+lm)*256 + k0;                          dst = (u16*)(ws + WRZ_OFF); }
        else if (a < 144) { nt = a - 128; s0 = Wih_d + (size_t)(512+nt*16+lm)*256 + k0;        dst = (u16*)(ws + WIN_OFF); }
        else              { nt = a - 144; s0 = Whh_d + (size_t)(512+nt*16+lm)*256 + k0;        dst = (u16*)(ws + WHN_OFF); }
        u32 wd[4];
        #pragma unroll
        for (int p = 0; p < 4; ++p) {
            float v0 = s0[2*p]   + (s1 ? s1[2*p]   : 0.f);
            float v1 = s0[2*p+1] + (s1 ? s1[2*p+1] : 0.f);
            wd[p] = (u32)f2h(v0) | ((u32)f2h(v1) << 16);
        }
        uint4 o; o.x = wd[0]; o.y = wd[1]; o.z = wd[2]; o.w = wd[3];
        *(uint4*)(dst + ((size_t)((nt * 8 + ks) * 64 + lane)) * 8) = o;
    } else if (gid < NFRAG + 2048) {
        int bid = gid - NFRAG;
        if (bid < 768) {
            ((float*)(ws + BG_OFF))[bid] = bih_e[bid] + (bid < 512 ? bhh_e[bid] : 0.f);
        } else if (bid < 1024) {
            int j = bid - 768;  ((float*)(ws + BHN_E_OFF))[j] = bhh_e[512 + j];
        } else if (bid < 1536) {
            int j = bid - 1024; ((float*)(ws + BDEC_OFF))[j] = bih_d[j] + bhh_d[j];
        } else if (bid < 1792) {
            int j = bid - 1536; ((float*)(ws + BDEC_OFF))[512 + j] = bih_d[512 + j];
        } else {
            int j = bid - 1792; ((float*)(ws + BDEC_OFF))[768 + j] = bhh_d[512 + j];
        }
    }
}

// ---------------------------------------------------------------------------
// gemm_gi: gi_x[m][g] = sum_k x[m][k]*Wih_e[g][k] + bias[g], m = b*512+t
// swapped operands: D[gate][m] so each lane holds 4 consecutive gates.
// ---------------------------------------------------------------------------
__global__ __launch_bounds__(256) void gemm_gi(const float* __restrict__ x, char* ws)
{
    extern __shared__ char smem[];
    ushort4* xl = (ushort4*)smem;  // [128 rows][64 8B-units], XOR-swizzled
    const u16* Wfrag = (const u16*)(ws + WIH_OFF);
    const float* bias = (const float*)(ws + BG_OFF);
    u16* gi = (u16*)(ws + GI_OFF);
    int tid = threadIdx.x;
    int m0 = blockIdx.x * 128;
    int n0 = blockIdx.y * 128;
    {   // stage x tile fp32->fp16 (full K=256)
        int row = tid >> 1, half = tid & 1;
        const float* src = x + (size_t)(m0 + row) * 256 + half * 128;
        #pragma unroll
        for (int q = 0; q < 32; ++q) {
            f32x4 v = *(const f32x4*)(src + q * 4);
            int vv = (row << 6) + (half * 32 + q);
            vv ^= ((row & 7) << 1);
            xl[vv] = make_ushort4(f2h(v.x), f2h(v.y), f2h(v.z), f2h(v.w));
        }
    }
    __syncthreads();
    int l = tid & 63, w = tid >> 6;
    int lm = l & 15, lg = l >> 4;
    int gh = w >> 1, mh = w & 1;
    const f32x4 Z4 = {0.f, 0.f, 0.f, 0.f};
    f32x4 acc[4][4];
    #pragma unroll
    for (int a = 0; a < 4; ++a)
        #pragma unroll
        for (int b = 0; b < 4; ++b) acc[a][b] = Z4;
    #pragma unroll
    for (int ks = 0; ks < 8; ++ks) {
        f16x8 xf[4], wf[4];
        #pragma unroll
        for (int mt = 0; mt < 4; ++mt) {
            int row = mh * 64 + mt * 16 + lm;
            int vv = (row << 6) + ((ks * 4 + lg) << 1);
            vv ^= ((row & 7) << 1);
            xf[mt] = __builtin_bit_cast(f16x8, *(const uint4*)&xl[vv]);
        }
        #pragma unroll
        for (int gt = 0; gt < 4; ++gt)
            wf[gt] = ldfrag(Wfrag, (n0 >> 4) + gh * 4 + gt, ks, l);
        #pragma unroll
        for (int gt = 0; gt < 4; ++gt)
            #pragma unroll
            for (int mt = 0; mt < 4; ++mt)
                acc[gt][mt] = __builtin_amdgcn_mfma_f32_16x16x32_f16(wf[gt], xf[mt], acc[gt][mt], 0, 0, 0);
    }
    #pragma unroll
    for (int gt = 0; gt < 4; ++gt) {
        int g0 = n0 + (gh * 4 + gt) * 16 + lg * 4;
        f32x4 bv = *(const f32x4*)(bias + g0);
        #pragma unroll
        for (int mt = 0; mt < 4; ++mt) {
            int m = m0 + mh * 64 + mt * 16 + lm;
            f32x4 v = acc[gt][mt] + bv;
            *(ushort4*)(gi + (size_t)m * 768 + g0) =
                make_ushort4(f2h(v.x), f2h(v.y), f2h(v.z), f2h(v.w));
        }
    }
}

// ---------------------------------------------------------------------------
// encoder: 8 WGs x 16 batch rows, 4 waves, all Whh_e (384KB fp16) in VGPRs.
// wave w owns h-cols [64w,64w+64): r/z/n ntiles {4w+i}, {16+4w+i}, {32+4w+i}.
// fp32 state in hreg[]; LDS h copy is fp16 operand-only.
// ---------------------------------------------------------------------------
__global__ __launch_bounds__(256, 1) void enc_kernel(char* ws, float* __restrict__ dout)
{
    __shared__ ushort4 hl[16 * 64];     // h fp16 [16][256], XOR-swizzled 8B units
    __shared__ float bhn_l[256];
    const u16* Wf = (const u16*)(ws + WHH_OFF);
    const u16* gi = (const u16*)(ws + GI_OFF);
    float* lat = dout + (size_t)B_ * T_ * H_;
    int tid = threadIdx.x;
    int l = tid & 63, w = tid >> 6;
    int lm = l & 15, lg = l >> 4, lg4 = lg * 4;
    int b0 = blockIdx.x * 16;

    bhn_l[tid] = ((const float*)(ws + BHN_E_OFF))[tid];
    #pragma unroll
    for (int q = 0; q < 4; ++q) hl[tid + q * 256] = make_ushort4(0, 0, 0, 0);

    f16x8 Wr[4][8], Wz[4][8], Wn[4][8];
    #pragma unroll
    for (int i = 0; i < 4; ++i)
        #pragma unroll
        for (int ks = 0; ks < 8; ++ks) {
            Wr[i][ks] = ldfrag(Wf, 4 * w + i, ks, l);
            Wz[i][ks] = ldfrag(Wf, 16 + 4 * w + i, ks, l);
            Wn[i][ks] = ldfrag(Wf, 32 + 4 * w + i, ks, l);
        }
    __syncthreads();

    const u16* gbase = gi + (size_t)(b0 + lm) * T_ * G3;
    ushort4 pfR[4], pfZ[4], pfN[4];
    #pragma unroll
    for (int i = 0; i < 4; ++i) {
        int j0 = (4 * w + i) * 16 + lg4;
        pfR[i] = *(const ushort4*)(gbase + j0);
        pfZ[i] = *(const ushort4*)(gbase + 256 + j0);
        pfN[i] = *(const ushort4*)(gbase + 512 + j0);
    }
    const f32x4 Z4 = {0.f, 0.f, 0.f, 0.f};
    f32x4 hreg[4];                      // fp32 state: rows lm, cols j0..j0+3
    #pragma unroll
    for (int i = 0; i < 4; ++i) hreg[i] = Z4;

    for (int t = 0; t < 512; ++t) {
        ushort4 hnew[4];
        // i-outer: acc[i] complete after 24 MFMAs; elementwise(i) overlaps i+1
        #pragma unroll
        for (int i = 0; i < 4; ++i) {
            f32x4 accR = Z4, accZ = Z4, accN = Z4;
            #pragma unroll
            for (int ks = 0; ks < 8; ++ks) {
                int vv = (lm << 6) + ((ks * 4 + lg) << 1);
                vv ^= ((lm & 7) << 1);
                f16x8 hb = __builtin_bit_cast(f16x8, *(const uint4*)&hl[vv]);
                accR = __builtin_amdgcn_mfma_f32_16x16x32_f16(Wr[i][ks], hb, accR, 0, 0, 0);
                accZ = __builtin_amdgcn_mfma_f32_16x16x32_f16(Wz[i][ks], hb, accZ, 0, 0, 0);
                accN = __builtin_amdgcn_mfma_f32_16x16x32_f16(Wn[i][ks], hb, accN, 0, 0, 0);
            }
            int j0 = (4 * w + i) * 16 + lg4;
            float bn0 = bhn_l[j0], bn1 = bhn_l[j0 + 1], bn2 = bhn_l[j0 + 2], bn3 = bhn_l[j0 + 3];
            float r0 = sigf(h2f(pfR[i].x) + accR.x), z0 = sigf(h2f(pfZ[i].x) + accZ.x);
            float n0 = tanhf_(h2f(pfN[i].x) + r0 * (accN.x + bn0));
            float h0 = n0 + z0 * (hreg[i].x - n0);
            float r1 = sigf(h2f(pfR[i].y) + accR.y), z1 = sigf(h2f(pfZ[i].y) + accZ.y);
            float n1 = tanhf_(h2f(pfN[i].y) + r1 * (accN.y + bn1));
            float h1 = n1 + z1 * (hreg[i].y - n1);
            float r2 = sigf(h2f(pfR[i].z) + accR.z), z2 = sigf(h2f(pfZ[i].z) + accZ.z);
            float n2 = tanhf_(h2f(pfN[i].z) + r2 * (accN.z + bn2));
            float h2 = n2 + z2 * (hreg[i].z - n2);
            float r3 = sigf(h2f(pfR[i].w) + accR.w), z3 = sigf(h2f(pfZ[i].w) + accZ.w);
            float n3 = tanhf_(h2f(pfN[i].w) + r3 * (accN.w + bn3));
            float h3 = n3 + z3 * (hreg[i].w - n3);
            f32x4 hv = {h0, h1, h2, h3};
            hreg[i] = hv;
            hnew[i] = make_ushort4(f2h(h0), f2h(h1), f2h(h2), f2h(h3));
            if (t == 511) {
                *(f32x4*)(lat + (size_t)(b0 + lm) * 256 + j0) = hv;
            }
        }
        __syncthreads();
        #pragma unroll
        for (int i = 0; i < 4; ++i) {
            int j0 = (4 * w + i) * 16 + lg4;
            int vh = (lm << 6) + (j0 >> 2);
            vh ^= ((lm & 7) << 1);
            hl[vh] = hnew[i];
        }
        int tn = (t + 1) & 511;
        const u16* gp = gbase + (size_t)tn * G3;
        #pragma unroll
        for (int i = 0; i < 4; ++i) {
            int j0 = (4 * w + i) * 16 + lg4;
            pfR[i] = *(const ushort4*)(gp + j0);
            pfZ[i] = *(const ushort4*)(gp + 256 + j0);
            pfN[i] = *(const ushort4*)(gp + 512 + j0);
        }
        __syncthreads();
    }
}

// ---------------------------------------------------------------------------
// decoder step 0: hx0 = cell(latents, 0); out[:,511,:] = hx0; ws.h1 = hx0
// ---------------------------------------------------------------------------
__global__ __launch_bounds__(256) void dec0_kernel(
    const float* __restrict__ Wih_d, const float* __restrict__ bih_d,
    const float* __restrict__ bhh_d, char* ws, float* __restrict__ dout)
{
    __shared__ float latl[256];
    int b = blockIdx.x, j = threadIdx.x;
    const float* latg = dout + (size_t)B_ * T_ * H_;
    latl[j] = latg[(size_t)b * 256 + j];
    __syncthreads();
    const float* wr = Wih_d + (size_t)j * 256;
    const float* wz = Wih_d + (size_t)(256 + j) * 256;
    const float* wn = Wih_d + (size_t)(512 + j) * 256;
    float sr = 0.f, sz = 0.f, sn = 0.f;
    #pragma unroll 4
    for (int k = 0; k < 256; ++k) {
        float h = latl[k];
        sr = fmaf(h, wr[k], sr); sz = fmaf(h, wz[k], sz); sn = fmaf(h, wn[k], sn);
    }
    float r = sigf(sr + bih_d[j] + bhh_d[j]);
    float z = sigf(sz + bih_d[256 + j] + bhh_d[256 + j]);
    float n = tanhf_(sn + bih_d[512 + j] + r * bhh_d[512 + j]);
    float h1v = (1.f - z) * n;
    ((float*)(ws + H1_OFF))[(size_t)b * 256 + j] = h1v;
    dout[((size_t)b * 512 + 511) * 256 + j] = h1v;
}

// ---------------------------------------------------------------------------
// decoder: steps 1..511. rz-sum + in weights (384KB) in VGPRs; hn (128KB) LDS.
// fp32 state in hreg[]; LDS h copy is fp16 operand-only.
// ---------------------------------------------------------------------------
__global__ __launch_bounds__(256, 1) void dec_kernel(char* ws, float* __restrict__ dout)
{
    extern __shared__ char smem[];
    uint4* whn = (uint4*)smem;                       // [16][8][64] fragments
    ushort4* hl = (ushort4*)(smem + 131072);         // h fp16, swizzled
    float* bias_l = (float*)(smem + 139264);         // [1024]
    const u16* Wrzf = (const u16*)(ws + WRZ_OFF);
    const u16* Winf = (const u16*)(ws + WIN_OFF);
    const uint4* Whnf = (const uint4*)(ws + WHN_OFF);
    const float* bdec = (const float*)(ws + BDEC_OFF);
    const float* h1 = (const float*)(ws + H1_OFF);
    int tid = threadIdx.x;
    int l = tid & 63, w = tid >> 6;
    int lm = l & 15, lg = l >> 4, lg4 = lg * 4;
    int b0 = blockIdx.x * 16;

    for (int q = 0; q < 32; ++q) whn[tid + q * 256] = Whnf[tid + q * 256];
    #pragma unroll
    for (int q = 0; q < 4; ++q) bias_l[tid + q * 256] = bdec[tid + q * 256];
    #pragma unroll
    for (int q = 0; q < 4; ++q) {
        int u = tid + q * 256;
        int row = u >> 6, cu = u & 63;
        const float* s = h1 + (size_t)(b0 + row) * 256 + cu * 4;
        int vv = u ^ ((row & 7) << 1);
        hl[vv] = make_ushort4(f2h(s[0]), f2h(s[1]), f2h(s[2]), f2h(s[3]));
    }
    f16x8 Wr[4][8], Wz[4][8], Wi[4][8];
    #pragma unroll
    for (int i = 0; i < 4; ++i)
        #pragma unroll
        for (int ks = 0; ks < 8; ++ks) {
            Wr[i][ks] = ldfrag(Wrzf, 4 * w + i, ks, l);
            Wz[i][ks] = ldfrag(Wrzf, 16 + 4 * w + i, ks, l);
            Wi[i][ks] = ldfrag(Winf, 4 * w + i, ks, l);
        }
    __syncthreads();
    const f32x4 Z4 = {0.f, 0.f, 0.f, 0.f};
    f32x4 hreg[4];                       // fp32 state
    #pragma unroll
    for (int i = 0; i < 4; ++i) {
        int j0 = (4 * w + i) * 16 + lg4;
        hreg[i] = *(const f32x4*)(h1 + (size_t)(b0 + lm) * 256 + j0);
    }

    for (int it = 1; it < 512; ++it) {
        ushort4 hnew[4];
        int trow = 511 - it;
        #pragma unroll
        for (int i = 0; i < 4; ++i) {
            int jb = (4 * w + i) * 16 + lg4;
            f32x4 accR = *(const f32x4*)(bias_l + jb);
            f32x4 accZ = *(const f32x4*)(bias_l + 256 + jb);
            f32x4 accI = *(const f32x4*)(bias_l + 512 + jb);
            f32x4 accN = Z4;
            #pragma unroll
            for (int ks = 0; ks < 8; ++ks) {
                int vv = (lm << 6) + ((ks * 4 + lg) << 1);
                vv ^= ((lm & 7) << 1);
                f16x8 hb = __builtin_bit_cast(f16x8, *(const uint4*)&hl[vv]);
                accR = __builtin_amdgcn_mfma_f32_16x16x32_f16(Wr[i][ks], hb, accR, 0, 0, 0);
                accZ = __builtin_amdgcn_mfma_f32_16x16x32_f16(Wz[i][ks], hb, accZ, 0, 0, 0);
                accI = __builtin_amdgcn_mfma_f32_16x16x32_f16(Wi[i][ks], hb, accI, 0, 0, 0);
                f16x8 wn = __builtin_bit_cast(f16x8, whn[((4 * w + i) * 8 + ks) * 64 + l]);
                accN = __builtin_amdgcn_mfma_f32_16x16x32_f16(wn, hb, accN, 0, 0, 0);
            }
            float bn0 = bias_l[768 + jb], bn1 = bias_l[768 + jb + 1];
            float bn2 = bias_l[768 + jb + 2], bn3 = bias_l[768 + jb + 3];
            float r0 = sigf(accR.x), z0 = sigf(accZ.x);
            float n0 = tanhf_(accI.x + r0 * (accN.x + bn0));
            float h0 = n0 + z0 * (hreg[i].x - n0);
            float r1 = sigf(accR.y), z1 = sigf(accZ.y);
            float n1 = tanhf_(accI.y + r1 * (accN.y + bn1));
            float h1v = n1 + z1 * (hreg[i].y - n1);
            float r2 = sigf(accR.z), z2 = sigf(accZ.z);
            float n2 = tanhf_(accI.z + r2 * (accN.z + bn2));
            float h2 = n2 + z2 * (hreg[i].z - n2);
            float r3 = sigf(accR.w), z3 = sigf(accZ.w);
            float n3 = tanhf_(accI.w + r3 * (accN.w + bn3));
            float h3 = n3 + z3 * (hreg[i].w - n3);
            f32x4 hv = {h0, h1v, h2, h3};
            hreg[i] = hv;
            hnew[i] = make_ushort4(f2h(h0), f2h(h1v), f2h(h2), f2h(h3));
            *(f32x4*)(dout + ((size_t)(b0 + lm) * 512 + trow) * 256 + jb) = hv;
        }
        __syncthreads();
        #pragma unroll
        for (int i = 0; i < 4; ++i) {
            int j0 = (4 * w + i) * 16 + lg4;
            int vh = (lm << 6) + (j0 >> 2);
            vh ^= ((lm & 7) << 1);
            hl[vh] = hnew[i];
        }
        __syncthreads();
    }
}

// ---------------------------------------------------------------------------
extern "C" void kernel_launch(void* const* d_in, const int* in_sizes, int n_in,
                              void* d_out, int out_size, void* d_ws, size_t ws_size,
                              hipStream_t stream)
{
    const float* x     = (const float*)d_in[0];
    const float* Wih_e = (const float*)d_in[1];
    const float* Whh_e = (const float*)d_in[2];
    const float* bih_e = (const float*)d_in[3];
    const float* bhh_e = (const float*)d_in[4];
    const float* Wih_d = (const float*)d_in[5];
    const float* Whh_d = (const float*)d_in[6];
    const float* bih_d = (const float*)d_in[7];
    const float* bhh_d = (const float*)d_in[8];
    char* ws = (char*)d_ws;
    float* out = (float*)d_out;

    (void)hipFuncSetAttribute((const void*)gemm_gi, hipFuncAttributeMaxDynamicSharedMemorySize, 65536);
    (void)hipFuncSetAttribute((const void*)dec_kernel, hipFuncAttributeMaxDynamicSharedMemorySize, DEC_LDS);

    prep_kernel<<<328, 256, 0, stream>>>(Wih_e, Whh_e, bih_e, bhh_e,
                                         Wih_d, Whh_d, bih_d, bhh_d, ws);
    gemm_gi<<<dim3(512, 6), 256, 65536, stream>>>(x, ws);
    enc_kernel<<<8, 256, 0, stream>>>(ws, out);
    dec0_kernel<<<128, 256, 0, stream>>>(Wih_d, bih_d, bhh_d, ws, out);
    dec_kernel<<<8, 256, DEC_LDS, stream>>>(ws, out);
}

// Round 3
// 2271.024 us; speedup vs baseline: 1.9652x; 1.9652x over previous
//
#include <hip/hip_runtime.h>

// ---------------------------------------------------------------------------
// GRU autoencoder: B=128, T=512, E=H=256.  fp16 operands, fp32 state in regs.
//  prep   : fp32->fp16 weight repack into MFMA fragment order + bias folding
//  gemm_gi: gi_x = x @ Wih_e^T + (bih_e + bhh_e[rz])   [65536 x 768] fp16
//  enc    : persistent recurrence, 8 WGs x 16 rows x 8 waves (2/SIMD),
//           gi staged via global_load_lds (coalesced), h double-buffered
//  dec0   : decoder step 0 (input=latents, state=0) - needs unfused Wih_d
//  dec    : persistent recurrence, rz-sum trick, 8 waves, hn-block in LDS
// ---------------------------------------------------------------------------

typedef unsigned short u16;
typedef unsigned int   u32;

typedef _Float16 f16x8 __attribute__((ext_vector_type(8)));
typedef float    f32x4 __attribute__((ext_vector_type(4)));

#define B_ 128
#define T_ 512
#define H_ 256
#define G3 768

// workspace layout (bytes)
#define GI_OFF     0ull                   // gi_x fp16 [65536][768]
#define WIH_OFF    100663296ull           // enc ih frag [48][8][64][8] fp16
#define WHH_OFF    101056512ull           // enc hh frag [48][8][64][8] fp16
#define WRZ_OFF    101449728ull           // dec rz-sum frag [32][8][64][8]
#define WIN_OFF    101711872ull           // dec in frag [16][8][64][8]
#define WHN_OFF    101842944ull           // dec hn frag [16][8][64][8]
#define BG_OFF     101974016ull           // gemm bias fp32 [768]
#define BHN_E_OFF  101977088ull           // enc bhh_n fp32 [256]
#define BDEC_OFF   101978112ull           // dec bias fp32 [1024] {brz,bin,bhn}
#define H1_OFF     101982208ull           // dec h1 fp32 [128][256]

// enc LDS layout
#define E_WN1_L   0                       // [8][8][64] uint4 = 65536
#define E_STG_L   65536                   // 2 x 16 rows x 1600B = 51200
#define E_HL_L    116736                  // 2 x 1024 x 8B = 16384
#define E_BHN_L   133120                  // 1024
#define ENC_LDS   134144

// dec LDS layout
#define D_WHN_L   0                       // [16][8][64] uint4 = 131072
#define D_HL_L    131072                  // 2 x 1024 x 8B = 16384
#define D_BIA_L   147456                  // 4096
#define DEC_LDS   151552

__device__ __forceinline__ float h2f(u16 u) {
    return (float)__builtin_bit_cast(_Float16, u);
}
__device__ __forceinline__ u16 f2h(float f) {
    _Float16 h = (_Float16)f;             // v_cvt_f16_f32, RNE
    return __builtin_bit_cast(u16, h);
}
__device__ __forceinline__ float sigf(float x) {
    return __builtin_amdgcn_rcpf(1.f + __builtin_amdgcn_exp2f(x * -1.4426950408889634f));
}
__device__ __forceinline__ float tanhf_(float x) {
    return 1.f - 2.f * __builtin_amdgcn_rcpf(1.f + __builtin_amdgcn_exp2f(x * 2.8853900817779268f));
}
__device__ __forceinline__ f16x8 ldfrag(const u16* base, int nt, int ks, int l) {
    return __builtin_bit_cast(f16x8, *(const uint4*)(base + ((size_t)((nt * 8 + ks) * 64 + l)) * 8));
}
__device__ __forceinline__ void gload_lds16(const void* g, void* l) {
    __builtin_amdgcn_global_load_lds(
        (const __attribute__((address_space(1))) unsigned int*)(g),
        (__attribute__((address_space(3))) unsigned int*)(l),
        16, 0, 0);
}
#define MFMA16(a, b, c) __builtin_amdgcn_mfma_f32_16x16x32_f16((a), (b), (c), 0, 0, 0)

// ---------------------------------------------------------------------------
// prep: pack weights into fragment order  W[nt*16 + lane%16][ks*32 + (lane/16)*8 + j]
// ---------------------------------------------------------------------------
__global__ __launch_bounds__(256) void prep_kernel(
    const float* __restrict__ Wih_e, const float* __restrict__ Whh_e,
    const float* __restrict__ bih_e, const float* __restrict__ bhh_e,
    const float* __restrict__ Wih_d, const float* __restrict__ Whh_d,
    const float* __restrict__ bih_d, const float* __restrict__ bhh_d,
    char* ws)
{
    int gid = blockIdx.x * 256 + threadIdx.x;
    const int NFRAG = 160 * 8 * 64;
    if (gid < NFRAG) {
        int lane = gid & 63;
        int ks = (gid >> 6) & 7;
        int a = gid >> 9;
        int lm = lane & 15, lg = lane >> 4;
        int k0 = ks * 32 + lg * 8;
        const float* s0; const float* s1 = nullptr; u16* dst; int nt;
        if (a < 48)       { nt = a;       s0 = Wih_e + (size_t)(nt*16+lm)*256 + k0;            dst = (u16*)(ws + WIH_OFF); }
        else if (a < 96)  { nt = a - 48;  s0 = Whh_e + (size_t)(nt*16+lm)*256 + k0;            dst = (u16*)(ws + WHH_OFF); }
        else if (a < 128) { nt = a - 96;  s0 = Wih_d + (size_t)(nt*16+lm)*256 + k0;
                            s1 = Whh_d + (size_t)(nt*16+lm)*256 + k0;                          dst = (u16*)(ws + WRZ_OFF); }
        else if (a < 144) { nt = a - 128; s0 = Wih_d + (size_t)(512+nt*16+lm)*256 + k0;        dst = (u16*)(ws + WIN_OFF); }
        else              { nt = a - 144; s0 = Whh_d + (size_t)(512+nt*16+lm)*256 + k0;        dst = (u16*)(ws + WHN_OFF); }
        u32 wd[4];
        #pragma unroll
        for (int p = 0; p < 4; ++p) {
            float v0 = s0[2*p]   + (s1 ? s1[2*p]   : 0.f);
            float v1 = s0[2*p+1] + (s1 ? s1[2*p+1] : 0.f);
            wd[p] = (u32)f2h(v0) | ((u32)f2h(v1) << 16);
        }
        uint4 o; o.x = wd[0]; o.y = wd[1]; o.z = wd[2]; o.w = wd[3];
        *(uint4*)(dst + ((size_t)((nt * 8 + ks) * 64 + lane)) * 8) = o;
    } else if (gid < NFRAG + 2048) {
        int bid = gid - NFRAG;
        if (bid < 768) {
            ((float*)(ws + BG_OFF))[bid] = bih_e[bid] + (bid < 512 ? bhh_e[bid] : 0.f);
        } else if (bid < 1024) {
            int j = bid - 768;  ((float*)(ws + BHN_E_OFF))[j] = bhh_e[512 + j];
        } else if (bid < 1536) {
            int j = bid - 1024; ((float*)(ws + BDEC_OFF))[j] = bih_d[j] + bhh_d[j];
        } else if (bid < 1792) {
            int j = bid - 1536; ((float*)(ws + BDEC_OFF))[512 + j] = bih_d[512 + j];
        } else {
            int j = bid - 1792; ((float*)(ws + BDEC_OFF))[768 + j] = bhh_d[512 + j];
        }
    }
}

// ---------------------------------------------------------------------------
// gemm_gi: gi_x[m][g] = sum_k x[m][k]*Wih_e[g][k] + bias[g], m = b*512+t
// ---------------------------------------------------------------------------
__global__ __launch_bounds__(256) void gemm_gi(const float* __restrict__ x, char* ws)
{
    extern __shared__ char smem[];
    ushort4* xl = (ushort4*)smem;  // [128 rows][64 8B-units], XOR-swizzled
    const u16* Wfrag = (const u16*)(ws + WIH_OFF);
    const float* bias = (const float*)(ws + BG_OFF);
    u16* gi = (u16*)(ws + GI_OFF);
    int tid = threadIdx.x;
    int m0 = blockIdx.x * 128;
    int n0 = blockIdx.y * 128;
    {   // stage x tile fp32->fp16 (full K=256)
        int row = tid >> 1, half = tid & 1;
        const float* src = x + (size_t)(m0 + row) * 256 + half * 128;
        #pragma unroll
        for (int q = 0; q < 32; ++q) {
            f32x4 v = *(const f32x4*)(src + q * 4);
            int vv = (row << 6) + (half * 32 + q);
            vv ^= ((row & 7) << 1);
            xl[vv] = make_ushort4(f2h(v.x), f2h(v.y), f2h(v.z), f2h(v.w));
        }
    }
    __syncthreads();
    int l = tid & 63, w = tid >> 6;
    int lm = l & 15, lg = l >> 4;
    int gh = w >> 1, mh = w & 1;
    const f32x4 Z4 = {0.f, 0.f, 0.f, 0.f};
    f32x4 acc[4][4];
    #pragma unroll
    for (int a = 0; a < 4; ++a)
        #pragma unroll
        for (int b = 0; b < 4; ++b) acc[a][b] = Z4;
    #pragma unroll
    for (int ks = 0; ks < 8; ++ks) {
        f16x8 xf[4], wf[4];
        #pragma unroll
        for (int mt = 0; mt < 4; ++mt) {
            int row = mh * 64 + mt * 16 + lm;
            int vv = (row << 6) + ((ks * 4 + lg) << 1);
            vv ^= ((row & 7) << 1);
            xf[mt] = __builtin_bit_cast(f16x8, *(const uint4*)&xl[vv]);
        }
        #pragma unroll
        for (int gt = 0; gt < 4; ++gt)
            wf[gt] = ldfrag(Wfrag, (n0 >> 4) + gh * 4 + gt, ks, l);
        #pragma unroll
        for (int gt = 0; gt < 4; ++gt)
            #pragma unroll
            for (int mt = 0; mt < 4; ++mt)
                acc[gt][mt] = MFMA16(wf[gt], xf[mt], acc[gt][mt]);
    }
    #pragma unroll
    for (int gt = 0; gt < 4; ++gt) {
        int g0 = n0 + (gh * 4 + gt) * 16 + lg * 4;
        f32x4 bv = *(const f32x4*)(bias + g0);
        #pragma unroll
        for (int mt = 0; mt < 4; ++mt) {
            int m = m0 + mh * 64 + mt * 16 + lm;
            f32x4 v = acc[gt][mt] + bv;
            *(ushort4*)(gi + (size_t)m * 768 + g0) =
                make_ushort4(f2h(v.x), f2h(v.y), f2h(v.z), f2h(v.w));
        }
    }
}

// ---------------------------------------------------------------------------
// encoder: 8 WGs x 16 rows, 8 waves (2/SIMD). Wave w owns h-cols [32w,32w+32).
// regs: Wr[2][8], Wz[2][8], Wn-even[8] (160 VGPR). LDS: odd n-ntiles, gi stage
// (dbuf, global_load_lds, row stride 1600B), h dbuf (1 barrier/step).
// ---------------------------------------------------------------------------
__global__ __launch_bounds__(512, 2) void enc_kernel(char* ws, float* __restrict__ dout)
{
    extern __shared__ char smem[];
    uint4*   wn1   = (uint4*)(smem + E_WN1_L);     // [8 waves][8 ks][64]
    char*    stg   = smem + E_STG_L;               // 2 x [16][1600]
    ushort4* hl    = (ushort4*)(smem + E_HL_L);    // 2 x 1024 units
    float*   bhn_l = (float*)(smem + E_BHN_L);
    const u16* Wf = (const u16*)(ws + WHH_OFF);
    const u16* gi = (const u16*)(ws + GI_OFF);
    float* lat = dout + (size_t)B_ * T_ * H_;
    int tid = threadIdx.x;
    int l = tid & 63, w = tid >> 6;
    int lm = l & 15, lg = l >> 4, lg4 = lg * 4;
    int b0 = blockIdx.x * 16;

    if (tid < 256) bhn_l[tid] = ((const float*)(ws + BHN_E_OFF))[tid];
    #pragma unroll
    for (int q = 0; q < 2; ++q) hl[tid + q * 512] = make_ushort4(0, 0, 0, 0);   // hl[0]=0
    #pragma unroll
    for (int p = 0; p < 8; ++p) {      // odd n-ntiles -> LDS
        int u = tid + p * 512;
        int no = u >> 9, ks = (u >> 6) & 7, ll = u & 63;
        wn1[u] = *(const uint4*)(Wf + ((size_t)(((32 + 2 * no + 1) * 8 + ks) * 64 + ll)) * 8);
    }
    f16x8 Wr[2][8], Wz[2][8], Wn0[8];
    #pragma unroll
    for (int i = 0; i < 2; ++i)
        #pragma unroll
        for (int ks = 0; ks < 8; ++ks) {
            Wr[i][ks] = ldfrag(Wf, 2 * w + i, ks, l);
            Wz[i][ks] = ldfrag(Wf, 16 + 2 * w + i, ks, l);
        }
    #pragma unroll
    for (int ks = 0; ks < 8; ++ks) Wn0[ks] = ldfrag(Wf, 32 + 2 * w, ks, l);

    // gi staging offsets (u16 units); 25 windows of 1024B per step
    u32 goff[4];
    #pragma unroll
    for (int q = 0; q < 4; ++q) {
        int s = w + q * 8; if (s > 24) s = 24;
        int u = s * 64 + l;
        int row = u / 100, c = u % 100; if (c > 95) c = 95;
        goff[q] = ((u32)(b0 + row) * T_) * G3 + (u32)c * 8;
    }
    // prologue: stage t=0 into buf 0
    {
        #pragma unroll
        for (int q = 0; q < 4; ++q) {
            int s = w + q * 8;
            if (q < 3 || w == 0)
                gload_lds16(gi + goff[q], stg + s * 1024);
        }
    }
    __syncthreads();

    const f32x4 Z4 = {0.f, 0.f, 0.f, 0.f};
    f32x4 hreg[2] = {Z4, Z4};
    int cur = 0;

    for (int t = 0; t < 512; ++t) {
        int nxt = cur ^ 1;
        int tn = (t + 1) & 511;
        {   // prefetch t+1 (completion enforced by end-of-step barrier)
            char* sb = stg + nxt * 25600;
            #pragma unroll
            for (int q = 0; q < 4; ++q) {
                int s = w + q * 8;
                if (q < 3 || w == 0)
                    gload_lds16(gi + goff[q] + (u32)tn * G3, sb + s * 1024);
            }
        }
        const ushort4* hc = hl + cur * 1024;
        ushort4* hd = hl + nxt * 1024;
        const char* sc = stg + cur * 25600;

        f32x4 aR[2], aZ[2], aN[2];
        #pragma unroll
        for (int i = 0; i < 2; ++i) { aR[i] = Z4; aZ[i] = Z4; aN[i] = Z4; }
        #pragma unroll
        for (int ks = 0; ks < 8; ++ks) {
            int vv = (lm << 6) + ((ks * 4 + lg) << 1);
            vv ^= ((lm & 7) << 1);
            f16x8 hb = __builtin_bit_cast(f16x8, *(const uint4*)&hc[vv]);
            f16x8 wn1v = __builtin_bit_cast(f16x8, wn1[(w * 8 + ks) * 64 + l]);
            aR[0] = MFMA16(Wr[0][ks], hb, aR[0]);
            aZ[0] = MFMA16(Wz[0][ks], hb, aZ[0]);
            aN[0] = MFMA16(Wn0[ks],   hb, aN[0]);
            aR[1] = MFMA16(Wr[1][ks], hb, aR[1]);
            aZ[1] = MFMA16(Wz[1][ks], hb, aZ[1]);
            aN[1] = MFMA16(wn1v,      hb, aN[1]);
        }
        ushort4 hnew[2];
        const char* rb = sc + lm * 1600;
        #pragma unroll
        for (int i = 0; i < 2; ++i) {
            int j0 = (2 * w + i) * 16 + lg4;
            ushort4 gR = *(const ushort4*)(rb + j0 * 2);
            ushort4 gZ = *(const ushort4*)(rb + 512 + j0 * 2);
            ushort4 gN = *(const ushort4*)(rb + 1024 + j0 * 2);
            float bn0 = bhn_l[j0], bn1 = bhn_l[j0 + 1], bn2 = bhn_l[j0 + 2], bn3 = bhn_l[j0 + 3];
            float r0 = sigf(h2f(gR.x) + aR[i].x), z0 = sigf(h2f(gZ.x) + aZ[i].x);
            float n0 = tanhf_(h2f(gN.x) + r0 * (aN[i].x + bn0));
            float h0 = n0 + z0 * (hreg[i].x - n0);
            float r1 = sigf(h2f(gR.y) + aR[i].y), z1 = sigf(h2f(gZ.y) + aZ[i].y);
            float n1 = tanhf_(h2f(gN.y) + r1 * (aN[i].y + bn1));
            float h1 = n1 + z1 * (hreg[i].y - n1);
            float r2 = sigf(h2f(gR.z) + aR[i].z), z2 = sigf(h2f(gZ.z) + aZ[i].z);
            float n2 = tanhf_(h2f(gN.z) + r2 * (aN[i].z + bn2));
            float h2 = n2 + z2 * (hreg[i].z - n2);
            float r3 = sigf(h2f(gR.w) + aR[i].w), z3 = sigf(h2f(gZ.w) + aZ[i].w);
            float n3 = tanhf_(h2f(gN.w) + r3 * (aN[i].w + bn3));
            float h3 = n3 + z3 * (hreg[i].w - n3);
            f32x4 hv = {h0, h1, h2, h3};
            hreg[i] = hv;
            hnew[i] = make_ushort4(f2h(h0), f2h(h1), f2h(h2), f2h(h3));
            if (t == 511) *(f32x4*)(lat + (size_t)(b0 + lm) * 256 + j0) = hv;
        }
        #pragma unroll
        for (int i = 0; i < 2; ++i) {
            int j0 = (2 * w + i) * 16 + lg4;
            int vh = (lm << 6) + (j0 >> 2);
            vh ^= ((lm & 7) << 1);
            hd[vh] = hnew[i];
        }
        __syncthreads();
        cur = nxt;
    }
}

// ---------------------------------------------------------------------------
// decoder step 0: hx0 = cell(latents, 0); out[:,511,:] = hx0; ws.h1 = hx0
// ---------------------------------------------------------------------------
__global__ __launch_bounds__(256) void dec0_kernel(
    const float* __restrict__ Wih_d, const float* __restrict__ bih_d,
    const float* __restrict__ bhh_d, char* ws, float* __restrict__ dout)
{
    __shared__ float latl[256];
    int b = blockIdx.x, j = threadIdx.x;
    const float* latg = dout + (size_t)B_ * T_ * H_;
    latl[j] = latg[(size_t)b * 256 + j];
    __syncthreads();
    const float* wr = Wih_d + (size_t)j * 256;
    const float* wz = Wih_d + (size_t)(256 + j) * 256;
    const float* wn = Wih_d + (size_t)(512 + j) * 256;
    float sr = 0.f, sz = 0.f, sn = 0.f;
    #pragma unroll 4
    for (int k = 0; k < 256; ++k) {
        float h = latl[k];
        sr = fmaf(h, wr[k], sr); sz = fmaf(h, wz[k], sz); sn = fmaf(h, wn[k], sn);
    }
    float r = sigf(sr + bih_d[j] + bhh_d[j]);
    float z = sigf(sz + bih_d[256 + j] + bhh_d[256 + j]);
    float n = tanhf_(sn + bih_d[512 + j] + r * bhh_d[512 + j]);
    float h1v = (1.f - z) * n;
    ((float*)(ws + H1_OFF))[(size_t)b * 256 + j] = h1v;
    dout[((size_t)b * 512 + 511) * 256 + j] = h1v;
}

// ---------------------------------------------------------------------------
// decoder: steps 1..511. 8 waves; Wr/Wz/Wi regs (192 VGPR), hn-block in LDS.
// ---------------------------------------------------------------------------
__global__ __launch_bounds__(512, 2) void dec_kernel(char* ws, float* __restrict__ dout)
{
    extern __shared__ char smem[];
    uint4*   whn    = (uint4*)(smem + D_WHN_L);    // [16][8][64]
    ushort4* hl     = (ushort4*)(smem + D_HL_L);   // 2 x 1024
    float*   bias_l = (float*)(smem + D_BIA_L);    // [1024]
    const u16* Wrzf = (const u16*)(ws + WRZ_OFF);
    const u16* Winf = (const u16*)(ws + WIN_OFF);
    const uint4* Whnf = (const uint4*)(ws + WHN_OFF);
    const float* bdec = (const float*)(ws + BDEC_OFF);
    const float* h1 = (const float*)(ws + H1_OFF);
    int tid = threadIdx.x;
    int l = tid & 63, w = tid >> 6;
    int lm = l & 15, lg = l >> 4, lg4 = lg * 4;
    int b0 = blockIdx.x * 16;

    #pragma unroll
    for (int p = 0; p < 16; ++p) { int u = tid + p * 512; whn[u] = Whnf[u]; }
    #pragma unroll
    for (int q = 0; q < 2; ++q) bias_l[tid + q * 512] = bdec[tid + q * 512];
    #pragma unroll
    for (int q = 0; q < 2; ++q) {      // hl[0] <- fp16(h1)
        int u = tid + q * 512;
        int row = u >> 6, cu = u & 63;
        const float* s = h1 + (size_t)(b0 + row) * 256 + cu * 4;
        int vv = u ^ ((row & 7) << 1);
        hl[vv] = make_ushort4(f2h(s[0]), f2h(s[1]), f2h(s[2]), f2h(s[3]));
    }
    f16x8 Wr[2][8], Wz[2][8], Wi[2][8];
    #pragma unroll
    for (int i = 0; i < 2; ++i)
        #pragma unroll
        for (int ks = 0; ks < 8; ++ks) {
            Wr[i][ks] = ldfrag(Wrzf, 2 * w + i, ks, l);
            Wz[i][ks] = ldfrag(Wrzf, 16 + 2 * w + i, ks, l);
            Wi[i][ks] = ldfrag(Winf, 2 * w + i, ks, l);
        }
    const f32x4 Z4 = {0.f, 0.f, 0.f, 0.f};
    f32x4 hreg[2];
    #pragma unroll
    for (int i = 0; i < 2; ++i) {
        int j0 = (2 * w + i) * 16 + lg4;
        hreg[i] = *(const f32x4*)(h1 + (size_t)(b0 + lm) * 256 + j0);
    }
    __syncthreads();
    int cur = 0;

    for (int it = 1; it < 512; ++it) {
        int nxt = cur ^ 1;
        int trow = 511 - it;
        const ushort4* hc = hl + cur * 1024;
        ushort4* hd = hl + nxt * 1024;

        f32x4 aR[2], aZ[2], aI[2], aN[2];
        #pragma unroll
        for (int i = 0; i < 2; ++i) {
            int jb = (2 * w + i) * 16 + lg4;
            aR[i] = *(const f32x4*)(bias_l + jb);
            aZ[i] = *(const f32x4*)(bias_l + 256 + jb);
            aI[i] = *(const f32x4*)(bias_l + 512 + jb);
            aN[i] = Z4;
        }
        #pragma unroll
        for (int ks = 0; ks < 8; ++ks) {
            int vv = (lm << 6) + ((ks * 4 + lg) << 1);
            vv ^= ((lm & 7) << 1);
            f16x8 hb = __builtin_bit_cast(f16x8, *(const uint4*)&hc[vv]);
            f16x8 wn0 = __builtin_bit_cast(f16x8, whn[((2 * w) * 8 + ks) * 64 + l]);
            f16x8 wn1 = __builtin_bit_cast(f16x8, whn[((2 * w + 1) * 8 + ks) * 64 + l]);
            aR[0] = MFMA16(Wr[0][ks], hb, aR[0]);
            aZ[0] = MFMA16(Wz[0][ks], hb, aZ[0]);
            aI[0] = MFMA16(Wi[0][ks], hb, aI[0]);
            aN[0] = MFMA16(wn0,       hb, aN[0]);
            aR[1] = MFMA16(Wr[1][ks], hb, aR[1]);
            aZ[1] = MFMA16(Wz[1][ks], hb, aZ[1]);
            aI[1] = MFMA16(Wi[1][ks], hb, aI[1]);
            aN[1] = MFMA16(wn1,       hb, aN[1]);
        }
        ushort4 hnew[2];
        #pragma unroll
        for (int i = 0; i < 2; ++i) {
            int jb = (2 * w + i) * 16 + lg4;
            float bn0 = bias_l[768 + jb], bn1 = bias_l[768 + jb + 1];
            float bn2 = bias_l[768 + jb + 2], bn3 = bias_l[768 + jb + 3];
            float r0 = sigf(aR[i].x), z0 = sigf(aZ[i].x);
            float n0 = tanhf_(aI[i].x + r0 * (aN[i].x + bn0));
            float h0 = n0 + z0 * (hreg[i].x - n0);
            float r1 = sigf(aR[i].y), z1 = sigf(aZ[i].y);
            float n1 = tanhf_(aI[i].y + r1 * (aN[i].y + bn1));
            float h1v = n1 + z1 * (hreg[i].y - n1);
            float r2 = sigf(aR[i].z), z2 = sigf(aZ[i].z);
            float n2 = tanhf_(aI[i].z + r2 * (aN[i].z + bn2));
            float h2 = n2 + z2 * (hreg[i].z - n2);
            float r3 = sigf(aR[i].w), z3 = sigf(aZ[i].w);
            float n3 = tanhf_(aI[i].w + r3 * (aN[i].w + bn3));
            float h3 = n3 + z3 * (hreg[i].w - n3);
            f32x4 hv = {h0, h1v, h2, h3};
            hreg[i] = hv;
            hnew[i] = make_ushort4(f2h(h0), f2h(h1v), f2h(h2), f2h(h3));
            *(f32x4*)(dout + ((size_t)(b0 + lm) * 512 + trow) * 256 + jb) = hv;
        }
        #pragma unroll
        for (int i = 0; i < 2; ++i) {
            int j0 = (2 * w + i) * 16 + lg4;
            int vh = (lm << 6) + (j0 >> 2);
            vh ^= ((lm & 7) << 1);
            hd[vh] = hnew[i];
        }
        __syncthreads();
        cur = nxt;
    }
}

// ---------------------------------------------------------------------------
extern "C" void kernel_launch(void* const* d_in, const int* in_sizes, int n_in,
                              void* d_out, int out_size, void* d_ws, size_t ws_size,
                              hipStream_t stream)
{
    const float* x     = (const float*)d_in[0];
    const float* Wih_e = (const float*)d_in[1];
    const float* Whh_e = (const float*)d_in[2];
    const float* bih_e = (const float*)d_in[3];
    const float* bhh_e = (const float*)d_in[4];
    const float* Wih_d = (const float*)d_in[5];
    const float* Whh_d = (const float*)d_in[6];
    const float* bih_d = (const float*)d_in[7];
    const float* bhh_d = (const float*)d_in[8];
    char* ws = (char*)d_ws;
    float* out = (float*)d_out;

    (void)hipFuncSetAttribute((const void*)gemm_gi, hipFuncAttributeMaxDynamicSharedMemorySize, 65536);
    (void)hipFuncSetAttribute((const void*)enc_kernel, hipFuncAttributeMaxDynamicSharedMemorySize, ENC_LDS);
    (void)hipFuncSetAttribute((const void*)dec_kernel, hipFuncAttributeMaxDynamicSharedMemorySize, DEC_LDS);

    prep_kernel<<<328, 256, 0, stream>>>(Wih_e, Whh_e, bih_e, bhh_e,
                                         Wih_d, Whh_d, bih_d, bhh_d, ws);
    gemm_gi<<<dim3(512, 6), 256, 65536, stream>>>(x, ws);
    enc_kernel<<<8, 512, ENC_LDS, stream>>>(ws, out);
    dec0_kernel<<<128, 256, 0, stream>>>(Wih_d, bih_d, bhh_d, ws, out);
    dec_kernel<<<8, 512, DEC_LDS, stream>>>(ws, out);
}